// Round 4
// baseline (659.159 us; speedup 1.0000x reference)
//
#include <hip/hip_runtime.h>
#include <math.h>

#define N_NODES  8192
#define FEATDIM  256
#define RCOUNT   65536
#define IN_RELS  64
#define M_PAIRS  1048576
#define LIST_CAP 2048

// ---------------- workspace layout (bytes) ----------------
// seq     : [0,           262144)   65536 floats
// cnt     : [262144,      294912)   8192 ints   (zeroed each call)
// cursor  : [294912,      327680)   8192 ints   (zeroed each call)
// rowptr  : [327680,      360512)   8193 ints (padded)
// perm    : [360512,      4554816)  1048576 ints
// total   : 4554816 bytes (~4.6 MB)
#define OFF_SEQ    0
#define OFF_CNT    262144
#define OFF_CURSOR 294912
#define OFF_ROWPTR 327680
#define OFF_PERM   360512
#define WS_NEEDED  4554816

// zero cnt + cursor (16384 contiguous ints starting at OFF_CNT)
__global__ void zero_kernel(int* __restrict__ p) {
    int i = blockIdx.x * blockDim.x + threadIdx.x;
    if (i < 16384) p[i] = 0;
}

// seq[r] = dot(rel[r, 0:64], W[0, 0:64])
__global__ void seq_kernel(const float* __restrict__ rel,
                           const float* __restrict__ W,
                           float* __restrict__ seq) {
    int r = blockIdx.x * blockDim.x + threadIdx.x;
    if (r >= RCOUNT) return;
    const float4* rr = reinterpret_cast<const float4*>(rel + (size_t)r * IN_RELS);
    const float4* ww = reinterpret_cast<const float4*>(W); // W[0] = first 64 floats
    float acc = 0.f;
#pragma unroll
    for (int k = 0; k < IN_RELS / 4; ++k) {
        float4 a = rr[k];
        float4 w = ww[k];
        acc += a.x * w.x + a.y * w.y + a.z * w.z + a.w * w.w;
    }
    seq[r] = acc;
}

__global__ void count_kernel(const int* __restrict__ src, int* __restrict__ cnt) {
    int p = blockIdx.x * blockDim.x + threadIdx.x;
    if (p < M_PAIRS) {
        int s = src[p];
        if (s >= 0 && s < N_NODES) atomicAdd(&cnt[s], 1);
    }
}

// exclusive scan of 8192 counts -> rowptr[0..8192], single block of 256 threads
__global__ void scan_kernel(const int* __restrict__ cnt, int* __restrict__ rowptr) {
    __shared__ int partial[256];
    int t = threadIdx.x;
    int base = t * 32;
    int local[32];
    int s = 0;
#pragma unroll
    for (int k = 0; k < 32; ++k) { local[k] = s; s += cnt[base + k]; }
    partial[t] = s;
    __syncthreads();
    if (t == 0) {
        int run = 0;
        for (int i = 0; i < 256; ++i) { int v = partial[i]; partial[i] = run; run += v; }
        rowptr[N_NODES] = run;
    }
    __syncthreads();
    int off = partial[t];
#pragma unroll
    for (int k = 0; k < 32; ++k) rowptr[base + k] = off + local[k];
}

__global__ void scatter_kernel(const int* __restrict__ src,
                               const int* __restrict__ rowptr,
                               int* __restrict__ cursor,
                               int* __restrict__ perm) {
    int p = blockIdx.x * blockDim.x + threadIdx.x;
    if (p >= M_PAIRS) return;
    int s = src[p];
    if (s < 0 || s >= N_NODES) return;
    int pos = atomicAdd(&cursor[s], 1);
    int idx = rowptr[s] + pos;
    if (idx >= 0 && idx < M_PAIRS) perm[idx] = p;
}

// One block per row: dedup/max-combine pairs, sparse softmax, SpMM row, ELU.
__launch_bounds__(256)
__global__ void row_kernel(const float* __restrict__ x,
                           const float* __restrict__ bias,
                           const int* __restrict__ pdst,
                           const int* __restrict__ prel,
                           const float* __restrict__ seq,
                           const int* __restrict__ rowptr,
                           const int* __restrict__ perm,
                           float* __restrict__ out) {
    __shared__ int   buf[N_NODES];     // 32 KB: float bits (>=0) or -1 sentinel
    __shared__ int   list_j[LIST_CAP]; // 8 KB
    __shared__ float list_l[LIST_CAP]; // 8 KB
    __shared__ float red[256];
    __shared__ int   nact;

    const int i = blockIdx.x;
    const int t = threadIdx.x;

    for (int k = t; k < N_NODES; k += 256) buf[k] = -1;
    if (t == 0) nact = 0;
    __syncthreads();

    int beg = rowptr[i], end = rowptr[i + 1];
    if (beg < 0) beg = 0;
    if (end > M_PAIRS) end = M_PAIRS;
    for (int e = beg + t; e < end; e += 256) {
        int p = perm[e];
        if (p < 0 || p >= M_PAIRS) continue;
        int j = pdst[p];
        if (j < 0 || j >= N_NODES) continue;
        float v = fmaxf(seq[prel[p]], 0.f);    // zeros-init scatter-max == clamp at 0
        atomicMax(&buf[j], __float_as_int(v)); // non-neg float: int order == float order
    }
    if (t == 0) atomicMax(&buf[i], 0);         // self-loop, value 0.0
    __syncthreads();

    // compact active entries
    for (int k = t; k < N_NODES; k += 256) {
        int b = buf[k];
        if (b >= 0) {
            int idx = atomicAdd(&nact, 1);
            if (idx < LIST_CAP) { list_j[idx] = k; list_l[idx] = __int_as_float(b); }
        }
    }
    __syncthreads();
    const int cnt = nact < LIST_CAP ? nact : LIST_CAP;

    // row max (all values >= 0)
    float m = 0.f;
    for (int e = t; e < cnt; e += 256) m = fmaxf(m, list_l[e]);
    red[t] = m;
    __syncthreads();
    for (int s2 = 128; s2 > 0; s2 >>= 1) {
        if (t < s2) red[t] = fmaxf(red[t], red[t + s2]);
        __syncthreads();
    }
    m = red[0];
    __syncthreads();

    // denominator
    float z = 0.f;
    for (int e = t; e < cnt; e += 256) z += expf(list_l[e] - m);
    red[t] = z;
    __syncthreads();
    for (int s2 = 128; s2 > 0; s2 >>= 1) {
        if (t < s2) red[t] += red[t + s2];
        __syncthreads();
    }
    const float invZ = 1.f / red[0];
    __syncthreads();

    // convert logits -> softmax weights in place
    for (int e = t; e < cnt; e += 256) list_l[e] = expf(list_l[e] - m) * invZ;
    __syncthreads();

    // accumulate: thread t owns feature channel t; unroll by 4 for ILP
    float acc0 = 0.f, acc1 = 0.f, acc2 = 0.f, acc3 = 0.f;
    int e = 0;
    for (; e + 4 <= cnt; e += 4) {
        acc0 += list_l[e + 0] * x[(size_t)list_j[e + 0] * FEATDIM + t];
        acc1 += list_l[e + 1] * x[(size_t)list_j[e + 1] * FEATDIM + t];
        acc2 += list_l[e + 2] * x[(size_t)list_j[e + 2] * FEATDIM + t];
        acc3 += list_l[e + 3] * x[(size_t)list_j[e + 3] * FEATDIM + t];
    }
    for (; e < cnt; ++e) acc0 += list_l[e] * x[(size_t)list_j[e] * FEATDIM + t];
    float v = (acc0 + acc1) + (acc2 + acc3) + bias[t];
    out[(size_t)i * FEATDIM + t] = v > 0.f ? v : expm1f(v);
}

extern "C" void kernel_launch(void* const* d_in, const int* in_sizes, int n_in,
                              void* d_out, int out_size, void* d_ws, size_t ws_size,
                              hipStream_t stream) {
    // defensive gates: never scribble out-of-bounds even if harness geometry
    // differs from expectations (a clean validation failure beats a dead container)
    if (ws_size < (size_t)WS_NEEDED) return;
    if (out_size < N_NODES * FEATDIM) return;
    if (n_in < 8) return;

    const float* x        = (const float*)d_in[0];
    const float* rel      = (const float*)d_in[1];
    const float* W        = (const float*)d_in[2];
    const float* bias     = (const float*)d_in[3];
    // d_in[4] = adj : intentionally unused (reconstructed from pairs + diagonal)
    const int*   pair_src = (const int*)d_in[5];
    const int*   pair_dst = (const int*)d_in[6];
    const int*   pair_rel = (const int*)d_in[7];
    float* out = (float*)d_out;

    char* ws = (char*)d_ws;
    float* seq    = (float*)(ws + OFF_SEQ);
    int*   cnt    = (int*)(ws + OFF_CNT);
    int*   cursor = (int*)(ws + OFF_CURSOR);
    int*   rowptr = (int*)(ws + OFF_ROWPTR);
    int*   perm   = (int*)(ws + OFF_PERM);

    zero_kernel<<<64, 256, 0, stream>>>(cnt);  // zeros cnt AND cursor (contiguous)
    seq_kernel<<<RCOUNT / 256, 256, 0, stream>>>(rel, W, seq);
    count_kernel<<<M_PAIRS / 256, 256, 0, stream>>>(pair_src, cnt);
    scan_kernel<<<1, 256, 0, stream>>>(cnt, rowptr);
    scatter_kernel<<<M_PAIRS / 256, 256, 0, stream>>>(pair_src, rowptr, cursor, perm);
    row_kernel<<<N_NODES, 256, 0, stream>>>(x, bias, pair_dst, pair_rel, seq,
                                            rowptr, perm, out);
}

// Round 5
// 561.902 us; speedup vs baseline: 1.1731x; 1.1731x over previous
//
#include <hip/hip_runtime.h>
#include <math.h>

#define N_NODES  8192
#define FEATDIM  256
#define RCOUNT   65536
#define IN_RELS  64
#define M_PAIRS  1048576
#define LIST_CAP 1024      // dedup LDS list cap (actual row degree ~128, max ~180)
#define LCAP_ST  256       // stored per-row list cap

// ---------------- workspace layout (bytes) ----------------
#define OFF_SEQ    0          // 65536 f32           -> 262144
#define OFF_CNT    262144     // 8192 i32 (zeroed)   -> 294912
#define OFF_CURSOR 294912     // 8192 i32 (zeroed)   -> 327680
#define OFF_ROWPTR 327680     // 8193 i32 (padded)   -> 360512
#define OFF_PERM   360512     // 1M i32              -> 4554816
#define WS_NEED1   4554816
#define OFF_ROWCNT 4554816    // 8192 i32            -> 4587584
#define OFF_JL     4587584    // 8192*256 i32        -> 12976192
#define OFF_WL     12976192   // 8192*256 f32        -> 21364800
#define WS_NEED2   21364800

// zero cnt + cursor (16384 contiguous ints starting at OFF_CNT)
__global__ void zero_kernel(int* __restrict__ p) {
    int i = blockIdx.x * blockDim.x + threadIdx.x;
    if (i < 16384) p[i] = 0;
}

// seq[r] = dot(rel[r, 0:64], W[0, 0:64])
__global__ void seq_kernel(const float* __restrict__ rel,
                           const float* __restrict__ W,
                           float* __restrict__ seq) {
    int r = blockIdx.x * blockDim.x + threadIdx.x;
    if (r >= RCOUNT) return;
    const float4* rr = reinterpret_cast<const float4*>(rel + (size_t)r * IN_RELS);
    const float4* ww = reinterpret_cast<const float4*>(W);
    float acc = 0.f;
#pragma unroll
    for (int k = 0; k < IN_RELS / 4; ++k) {
        float4 a = rr[k];
        float4 w = ww[k];
        acc += a.x * w.x + a.y * w.y + a.z * w.z + a.w * w.w;
    }
    seq[r] = acc;
}

__global__ void count_kernel(const int* __restrict__ src, int* __restrict__ cnt) {
    int p = blockIdx.x * blockDim.x + threadIdx.x;
    if (p < M_PAIRS) {
        int s = src[p];
        if (s >= 0 && s < N_NODES) atomicAdd(&cnt[s], 1);
    }
}

// exclusive scan of 8192 counts -> rowptr[0..8192], single block of 256 threads
__global__ void scan_kernel(const int* __restrict__ cnt, int* __restrict__ rowptr) {
    __shared__ int partial[256];
    int t = threadIdx.x;
    int base = t * 32;
    int local[32];
    int s = 0;
#pragma unroll
    for (int k = 0; k < 32; ++k) { local[k] = s; s += cnt[base + k]; }
    partial[t] = s;
    __syncthreads();
    if (t == 0) {
        int run = 0;
        for (int i = 0; i < 256; ++i) { int v = partial[i]; partial[i] = run; run += v; }
        rowptr[N_NODES] = run;
    }
    __syncthreads();
    int off = partial[t];
#pragma unroll
    for (int k = 0; k < 32; ++k) rowptr[base + k] = off + local[k];
}

__global__ void scatter_kernel(const int* __restrict__ src,
                               const int* __restrict__ rowptr,
                               int* __restrict__ cursor,
                               int* __restrict__ perm) {
    int p = blockIdx.x * blockDim.x + threadIdx.x;
    if (p >= M_PAIRS) return;
    int s = src[p];
    if (s < 0 || s >= N_NODES) return;
    int pos = atomicAdd(&cursor[s], 1);
    int idx = rowptr[s] + pos;
    if (idx >= 0 && idx < M_PAIRS) perm[idx] = p;
}

// Per row: dedup/max-combine pairs, sparse softmax, write compact (j, w) list.
__launch_bounds__(256)
__global__ void attn_list_kernel(const int* __restrict__ pdst,
                                 const int* __restrict__ prel,
                                 const float* __restrict__ seq,
                                 const int* __restrict__ rowptr,
                                 const int* __restrict__ perm,
                                 int* __restrict__ jl,
                                 float* __restrict__ wl,
                                 int* __restrict__ rowcnt) {
    __shared__ int   buf[N_NODES];     // 32 KB: float bits (>=0) or -1 sentinel
    __shared__ int   list_j[LIST_CAP]; // 4 KB
    __shared__ float list_l[LIST_CAP]; // 4 KB
    __shared__ float red[256];
    __shared__ int   nact;

    const int i = blockIdx.x;
    const int t = threadIdx.x;

    for (int k = t; k < N_NODES; k += 256) buf[k] = -1;
    if (t == 0) nact = 0;
    __syncthreads();

    int beg = rowptr[i], end = rowptr[i + 1];
    if (beg < 0) beg = 0;
    if (end > M_PAIRS) end = M_PAIRS;
    for (int e = beg + t; e < end; e += 256) {
        int p = perm[e];
        if (p < 0 || p >= M_PAIRS) continue;
        int j = pdst[p];
        if (j < 0 || j >= N_NODES) continue;
        float v = fmaxf(seq[prel[p]], 0.f);    // zeros-init scatter-max == clamp at 0
        atomicMax(&buf[j], __float_as_int(v)); // non-neg float: int order == float order
    }
    if (t == 0) atomicMax(&buf[i], 0);         // self-loop, value 0.0
    __syncthreads();

    // compact active entries
    for (int k = t; k < N_NODES; k += 256) {
        int b = buf[k];
        if (b >= 0) {
            int idx = atomicAdd(&nact, 1);
            if (idx < LIST_CAP) { list_j[idx] = k; list_l[idx] = __int_as_float(b); }
        }
    }
    __syncthreads();
    const int cnt = nact < LIST_CAP ? nact : LIST_CAP;

    // row max (all values >= 0)
    float m = 0.f;
    for (int e = t; e < cnt; e += 256) m = fmaxf(m, list_l[e]);
    red[t] = m;
    __syncthreads();
    for (int s2 = 128; s2 > 0; s2 >>= 1) {
        if (t < s2) red[t] = fmaxf(red[t], red[t + s2]);
        __syncthreads();
    }
    m = red[0];
    __syncthreads();

    // denominator
    float z = 0.f;
    for (int e = t; e < cnt; e += 256) z += expf(list_l[e] - m);
    red[t] = z;
    __syncthreads();
    for (int s2 = 128; s2 > 0; s2 >>= 1) {
        if (t < s2) red[t] += red[t + s2];
        __syncthreads();
    }
    const float invZ = 1.f / red[0];
    __syncthreads();

    // write compact normalized list
    const int wcnt = cnt < LCAP_ST ? cnt : LCAP_ST;
    for (int e = t; e < wcnt; e += 256) {
        jl[i * LCAP_ST + e] = list_j[e];
        wl[i * LCAP_ST + e] = expf(list_l[e] - m) * invZ;
    }
    if (t == 0) rowcnt[i] = wcnt;
}

// grid (8192 rows, 2 feature-halves), 128 threads. Half-major dispatch keeps the
// active x working set at 4 MB (= one XCD L2) instead of 8 MB.
__launch_bounds__(128)
__global__ void spmm_kernel(const float* __restrict__ x,
                            const float* __restrict__ bias,
                            const int* __restrict__ jl,
                            const float* __restrict__ wl,
                            const int* __restrict__ rowcnt,
                            float* __restrict__ out) {
    __shared__ int   sj[LCAP_ST];
    __shared__ float sw[LCAP_ST];
    const int row = blockIdx.x;
    const int h   = blockIdx.y;
    const int t   = threadIdx.x;

    int cnt = rowcnt[row];
    if (cnt < 0) cnt = 0;
    if (cnt > LCAP_ST) cnt = LCAP_ST;
    for (int e = t; e < cnt; e += 128) {
        sj[e] = jl[row * LCAP_ST + e];
        sw[e] = wl[row * LCAP_ST + e];
    }
    __syncthreads();

    const float* xh = x + (size_t)h * 128 + t;
    float a0 = 0.f, a1 = 0.f, a2 = 0.f, a3 = 0.f;
    float a4 = 0.f, a5 = 0.f, a6 = 0.f, a7 = 0.f;
    int e = 0;
    for (; e + 8 <= cnt; e += 8) {
        a0 += sw[e + 0] * xh[(size_t)sj[e + 0] * FEATDIM];
        a1 += sw[e + 1] * xh[(size_t)sj[e + 1] * FEATDIM];
        a2 += sw[e + 2] * xh[(size_t)sj[e + 2] * FEATDIM];
        a3 += sw[e + 3] * xh[(size_t)sj[e + 3] * FEATDIM];
        a4 += sw[e + 4] * xh[(size_t)sj[e + 4] * FEATDIM];
        a5 += sw[e + 5] * xh[(size_t)sj[e + 5] * FEATDIM];
        a6 += sw[e + 6] * xh[(size_t)sj[e + 6] * FEATDIM];
        a7 += sw[e + 7] * xh[(size_t)sj[e + 7] * FEATDIM];
    }
    for (; e < cnt; ++e) a0 += sw[e] * xh[(size_t)sj[e] * FEATDIM];
    float v = ((a0 + a1) + (a2 + a3)) + ((a4 + a5) + (a6 + a7)) + bias[h * 128 + t];
    out[(size_t)row * FEATDIM + h * 128 + t] = v > 0.f ? v : expm1f(v);
}

// ---- fallback fused kernel (round-4 version) if ws is too small ----
__launch_bounds__(256)
__global__ void row_kernel(const float* __restrict__ x,
                           const float* __restrict__ bias,
                           const int* __restrict__ pdst,
                           const int* __restrict__ prel,
                           const float* __restrict__ seq,
                           const int* __restrict__ rowptr,
                           const int* __restrict__ perm,
                           float* __restrict__ out) {
    __shared__ int   buf[N_NODES];
    __shared__ int   list_j[LIST_CAP];
    __shared__ float list_l[LIST_CAP];
    __shared__ float red[256];
    __shared__ int   nact;

    const int i = blockIdx.x;
    const int t = threadIdx.x;

    for (int k = t; k < N_NODES; k += 256) buf[k] = -1;
    if (t == 0) nact = 0;
    __syncthreads();

    int beg = rowptr[i], end = rowptr[i + 1];
    if (beg < 0) beg = 0;
    if (end > M_PAIRS) end = M_PAIRS;
    for (int e = beg + t; e < end; e += 256) {
        int p = perm[e];
        if (p < 0 || p >= M_PAIRS) continue;
        int j = pdst[p];
        if (j < 0 || j >= N_NODES) continue;
        float v = fmaxf(seq[prel[p]], 0.f);
        atomicMax(&buf[j], __float_as_int(v));
    }
    if (t == 0) atomicMax(&buf[i], 0);
    __syncthreads();

    for (int k = t; k < N_NODES; k += 256) {
        int b = buf[k];
        if (b >= 0) {
            int idx = atomicAdd(&nact, 1);
            if (idx < LIST_CAP) { list_j[idx] = k; list_l[idx] = __int_as_float(b); }
        }
    }
    __syncthreads();
    const int cnt = nact < LIST_CAP ? nact : LIST_CAP;

    float m = 0.f;
    for (int e = t; e < cnt; e += 256) m = fmaxf(m, list_l[e]);
    red[t] = m;
    __syncthreads();
    for (int s2 = 128; s2 > 0; s2 >>= 1) {
        if (t < s2) red[t] = fmaxf(red[t], red[t + s2]);
        __syncthreads();
    }
    m = red[0];
    __syncthreads();

    float z = 0.f;
    for (int e = t; e < cnt; e += 256) z += expf(list_l[e] - m);
    red[t] = z;
    __syncthreads();
    for (int s2 = 128; s2 > 0; s2 >>= 1) {
        if (t < s2) red[t] += red[t + s2];
        __syncthreads();
    }
    const float invZ = 1.f / red[0];
    __syncthreads();

    for (int e = t; e < cnt; e += 256) list_l[e] = expf(list_l[e] - m) * invZ;
    __syncthreads();

    float acc0 = 0.f, acc1 = 0.f, acc2 = 0.f, acc3 = 0.f;
    int e = 0;
    for (; e + 4 <= cnt; e += 4) {
        acc0 += list_l[e + 0] * x[(size_t)list_j[e + 0] * FEATDIM + t];
        acc1 += list_l[e + 1] * x[(size_t)list_j[e + 1] * FEATDIM + t];
        acc2 += list_l[e + 2] * x[(size_t)list_j[e + 2] * FEATDIM + t];
        acc3 += list_l[e + 3] * x[(size_t)list_j[e + 3] * FEATDIM + t];
    }
    for (; e < cnt; ++e) acc0 += list_l[e] * x[(size_t)list_j[e] * FEATDIM + t];
    float v = (acc0 + acc1) + (acc2 + acc3) + bias[t];
    out[(size_t)i * FEATDIM + t] = v > 0.f ? v : expm1f(v);
}

extern "C" void kernel_launch(void* const* d_in, const int* in_sizes, int n_in,
                              void* d_out, int out_size, void* d_ws, size_t ws_size,
                              hipStream_t stream) {
    if (ws_size < (size_t)WS_NEED1) return;
    if (out_size < N_NODES * FEATDIM) return;
    if (n_in < 8) return;

    const float* x        = (const float*)d_in[0];
    const float* rel      = (const float*)d_in[1];
    const float* W        = (const float*)d_in[2];
    const float* bias     = (const float*)d_in[3];
    // d_in[4] = adj : intentionally unused (softmax reconstructed sparsely;
    // exp(-1e9 - m) underflows to exact fp32 zero, so dense == sparse)
    const int*   pair_src = (const int*)d_in[5];
    const int*   pair_dst = (const int*)d_in[6];
    const int*   pair_rel = (const int*)d_in[7];
    float* out = (float*)d_out;

    char* ws = (char*)d_ws;
    float* seq    = (float*)(ws + OFF_SEQ);
    int*   cnt    = (int*)(ws + OFF_CNT);
    int*   cursor = (int*)(ws + OFF_CURSOR);
    int*   rowptr = (int*)(ws + OFF_ROWPTR);
    int*   perm   = (int*)(ws + OFF_PERM);

    zero_kernel<<<64, 256, 0, stream>>>(cnt);  // zeros cnt AND cursor (contiguous)
    seq_kernel<<<RCOUNT / 256, 256, 0, stream>>>(rel, W, seq);
    count_kernel<<<M_PAIRS / 256, 256, 0, stream>>>(pair_src, cnt);
    scan_kernel<<<1, 256, 0, stream>>>(cnt, rowptr);
    scatter_kernel<<<M_PAIRS / 256, 256, 0, stream>>>(pair_src, rowptr, cursor, perm);

    if (ws_size >= (size_t)WS_NEED2) {
        int*   rowcnt = (int*)(ws + OFF_ROWCNT);
        int*   jl     = (int*)(ws + OFF_JL);
        float* wl     = (float*)(ws + OFF_WL);
        attn_list_kernel<<<N_NODES, 256, 0, stream>>>(pair_dst, pair_rel, seq,
                                                      rowptr, perm, jl, wl, rowcnt);
        spmm_kernel<<<dim3(N_NODES, 2), 128, 0, stream>>>(x, bias, jl, wl, rowcnt, out);
    } else {
        row_kernel<<<N_NODES, 256, 0, stream>>>(x, bias, pair_dst, pair_rel, seq,
                                                rowptr, perm, out);
    }
}

// Round 6
// 443.292 us; speedup vs baseline: 1.4870x; 1.2676x over previous
//
#include <hip/hip_runtime.h>
#include <math.h>

#define N_NODES  8192
#define FEATDIM  256
#define RCOUNT   65536
#define IN_RELS  64
#define M_PAIRS  1048576
#define LCAP     256        // per-row slot capacity (degree ~Poisson(128); P(>256)~1e-21)
#define HSIZE    512        // LDS hash slots (load factor <= 0.5)

// ---------------- workspace layout (bytes) ----------------
#define OFF_SEQ    0          // 65536 f32              -> 262144
#define OFF_CURSOR 262144     // 8192 i32 (zeroed)      -> 294912
#define OFF_ROWCNT 294912     // 8192 i32               -> 327680
#define OFF_JV     327680     // 8192*256 int2 (16 MB)  -> 17104896
#define OFF_JL     17104896   // 8192*256 i32  (8 MB)   -> 25493504
#define OFF_WL     25493504   // 8192*256 f32  (8 MB)   -> 33882112
#define WS_NEEDED  33882112

__global__ void zero_kernel(int* __restrict__ p) {
    int i = blockIdx.x * blockDim.x + threadIdx.x;
    if (i < N_NODES) p[i] = 0;
}

// seq[r] = dot(rel[r, 0:64], W[0, 0:64])
__global__ void seq_kernel(const float* __restrict__ rel,
                           const float* __restrict__ W,
                           float* __restrict__ seq) {
    int r = blockIdx.x * blockDim.x + threadIdx.x;
    if (r >= RCOUNT) return;
    const float4* rr = reinterpret_cast<const float4*>(rel + (size_t)r * IN_RELS);
    const float4* ww = reinterpret_cast<const float4*>(W);
    float acc = 0.f;
#pragma unroll
    for (int k = 0; k < IN_RELS / 4; ++k) {
        float4 a = rr[k];
        float4 w = ww[k];
        acc += a.x * w.x + a.y * w.y + a.z * w.z + a.w * w.w;
    }
    seq[r] = acc;
}

// Direct scatter: pair p -> row slot (no CSR). One packed 8B store per pair.
__global__ void scatter_direct_kernel(const int* __restrict__ src,
                                      const int* __restrict__ dst,
                                      const int* __restrict__ prel,
                                      const float* __restrict__ seq,
                                      int* __restrict__ cursor,
                                      int2* __restrict__ jv) {
    int p = blockIdx.x * blockDim.x + threadIdx.x;
    if (p >= M_PAIRS) return;
    int s = src[p];
    if (s < 0 || s >= N_NODES) return;
    int j = dst[p];
    if (j < 0 || j >= N_NODES) return;
    int r = prel[p];
    if (r < 0 || r >= RCOUNT) return;
    int pos = atomicAdd(&cursor[s], 1);
    if (pos < LCAP) {
        float v = fmaxf(seq[r], 0.f);   // zeros-init scatter-max == clamp at 0
        jv[(size_t)s * LCAP + pos] = make_int2(j, __float_as_int(v));
    }
}

// Per row: hash dedup/max (512-slot LDS), softmax over unique set, write (j,w).
__launch_bounds__(256)
__global__ void attn_hash_kernel(const int2* __restrict__ jv,
                                 const int* __restrict__ cursor,
                                 int* __restrict__ jl,
                                 float* __restrict__ wl,
                                 int* __restrict__ rowcnt) {
    __shared__ int   hkey[HSIZE];
    __shared__ int   hval[HSIZE];
    __shared__ float red[256];
    __shared__ int   nout;

    const int i = blockIdx.x;
    const int t = threadIdx.x;

    hkey[t] = -1;          hval[t] = -1;
    hkey[t + 256] = -1;    hval[t + 256] = -1;
    if (t == 0) nout = 0;
    __syncthreads();

    int cnt = cursor[i];
    if (cnt < 0) cnt = 0;
    if (cnt > LCAP) cnt = LCAP;

    for (int e = t; e < cnt; e += 256) {
        int2 p = jv[(size_t)i * LCAP + e];
        int j = p.x;
        unsigned slot = ((unsigned)j * 2654435761u >> 16) & (HSIZE - 1);
        for (;;) {
            int k = atomicCAS(&hkey[slot], -1, j);
            if (k == -1 || k == j) break;
            slot = (slot + 1) & (HSIZE - 1);
        }
        atomicMax(&hval[slot], p.y);   // p.y >= 0 as int (float bits of v>=0)
    }
    if (t == 0) {                      // self-loop, value 0.0f (bits == 0)
        int j = i;
        unsigned slot = ((unsigned)j * 2654435761u >> 16) & (HSIZE - 1);
        for (;;) {
            int k = atomicCAS(&hkey[slot], -1, j);
            if (k == -1 || k == j) break;
            slot = (slot + 1) & (HSIZE - 1);
        }
        atomicMax(&hval[slot], 0);
    }
    __syncthreads();

    // row max over present slots (all values >= 0, self-loop guarantees >= 0)
    float m = 0.f;
    {
        if (hkey[t] >= 0)       m = fmaxf(m, __int_as_float(hval[t]));
        if (hkey[t + 256] >= 0) m = fmaxf(m, __int_as_float(hval[t + 256]));
    }
    red[t] = m;
    __syncthreads();
    for (int s2 = 128; s2 > 0; s2 >>= 1) {
        if (t < s2) red[t] = fmaxf(red[t], red[t + s2]);
        __syncthreads();
    }
    m = red[0];
    __syncthreads();

    // denominator
    float z = 0.f;
    {
        if (hkey[t] >= 0)       z += expf(__int_as_float(hval[t]) - m);
        if (hkey[t + 256] >= 0) z += expf(__int_as_float(hval[t + 256]) - m);
    }
    red[t] = z;
    __syncthreads();
    for (int s2 = 128; s2 > 0; s2 >>= 1) {
        if (t < s2) red[t] += red[t + s2];
        __syncthreads();
    }
    const float invZ = 1.f / red[0];
    __syncthreads();

    // compact normalized weights
#pragma unroll
    for (int half = 0; half < 2; ++half) {
        int s = t + half * 256;
        int k = hkey[s];
        if (k >= 0) {
            int idx = atomicAdd(&nout, 1);
            jl[(size_t)i * LCAP + idx] = k;
            wl[(size_t)i * LCAP + idx] = expf(__int_as_float(hval[s]) - m) * invZ;
        }
    }
    __syncthreads();
    if (t == 0) rowcnt[i] = nout;
}

// grid (8192 rows, 4 feature-quarters), 64 threads (1 wave). y-major dispatch
// keeps the active x working set at 2 MB (= half an XCD L2).
__launch_bounds__(64)
__global__ void spmm_kernel(const float* __restrict__ x,
                            const float* __restrict__ bias,
                            const int* __restrict__ jl,
                            const float* __restrict__ wl,
                            const int* __restrict__ rowcnt,
                            float* __restrict__ out) {
    __shared__ int   sj[LCAP];
    __shared__ float sw[LCAP];
    const int row = blockIdx.x;
    const int q   = blockIdx.y;
    const int t   = threadIdx.x;

    int cnt = rowcnt[row];
    if (cnt < 0) cnt = 0;
    if (cnt > LCAP) cnt = LCAP;
    for (int e = t; e < cnt; e += 64) {
        sj[e] = jl[(size_t)row * LCAP + e];
        sw[e] = wl[(size_t)row * LCAP + e];
    }
    __syncthreads();

    const float* xq = x + (size_t)q * 64 + t;
    float a0 = 0.f, a1 = 0.f, a2 = 0.f, a3 = 0.f;
    float a4 = 0.f, a5 = 0.f, a6 = 0.f, a7 = 0.f;
    int e = 0;
    for (; e + 8 <= cnt; e += 8) {
        a0 += sw[e + 0] * xq[(size_t)sj[e + 0] * FEATDIM];
        a1 += sw[e + 1] * xq[(size_t)sj[e + 1] * FEATDIM];
        a2 += sw[e + 2] * xq[(size_t)sj[e + 2] * FEATDIM];
        a3 += sw[e + 3] * xq[(size_t)sj[e + 3] * FEATDIM];
        a4 += sw[e + 4] * xq[(size_t)sj[e + 4] * FEATDIM];
        a5 += sw[e + 5] * xq[(size_t)sj[e + 5] * FEATDIM];
        a6 += sw[e + 6] * xq[(size_t)sj[e + 6] * FEATDIM];
        a7 += sw[e + 7] * xq[(size_t)sj[e + 7] * FEATDIM];
    }
    for (; e < cnt; ++e) a0 += sw[e] * xq[(size_t)sj[e] * FEATDIM];
    float v = ((a0 + a1) + (a2 + a3)) + ((a4 + a5) + (a6 + a7)) + bias[q * 64 + t];
    out[(size_t)row * FEATDIM + q * 64 + t] = v > 0.f ? v : expm1f(v);
}

extern "C" void kernel_launch(void* const* d_in, const int* in_sizes, int n_in,
                              void* d_out, int out_size, void* d_ws, size_t ws_size,
                              hipStream_t stream) {
    // defensive gates: clean validation failure beats a dead container
    if (ws_size < (size_t)WS_NEEDED) return;
    if (out_size < N_NODES * FEATDIM) return;
    if (n_in < 8) return;

    const float* x        = (const float*)d_in[0];
    const float* rel      = (const float*)d_in[1];
    const float* W        = (const float*)d_in[2];
    const float* bias     = (const float*)d_in[3];
    // d_in[4] = adj : intentionally unused (softmax reconstructed sparsely;
    // exp(-1e9 - m) underflows to exact fp32 zero, so dense == sparse)
    const int*   pair_src = (const int*)d_in[5];
    const int*   pair_dst = (const int*)d_in[6];
    const int*   pair_rel = (const int*)d_in[7];
    float* out = (float*)d_out;

    char* ws = (char*)d_ws;
    float* seq    = (float*)(ws + OFF_SEQ);
    int*   cursor = (int*)(ws + OFF_CURSOR);
    int*   rowcnt = (int*)(ws + OFF_ROWCNT);
    int2*  jv     = (int2*)(ws + OFF_JV);
    int*   jl     = (int*)(ws + OFF_JL);
    float* wl     = (float*)(ws + OFF_WL);

    zero_kernel<<<N_NODES / 256, 256, 0, stream>>>(cursor);
    seq_kernel<<<RCOUNT / 256, 256, 0, stream>>>(rel, W, seq);
    scatter_direct_kernel<<<M_PAIRS / 256, 256, 0, stream>>>(pair_src, pair_dst,
                                                             pair_rel, seq, cursor, jv);
    attn_hash_kernel<<<N_NODES, 256, 0, stream>>>(jv, cursor, jl, wl, rowcnt);
    spmm_kernel<<<dim3(N_NODES, 4), 64, 0, stream>>>(x, bias, jl, wl, rowcnt, out);
}

// Round 7
// 436.350 us; speedup vs baseline: 1.5106x; 1.0159x over previous
//
#include <hip/hip_runtime.h>
#include <math.h>

#define N_NODES  8192
#define FEATDIM  256
#define RCOUNT   65536
#define IN_RELS  64
#define M_PAIRS  1048576
#define LCAP     256        // per-row slot capacity (degree ~Poisson(128); P(>256)~1e-21)
#define HSIZE    512        // LDS hash slots (load factor <= 0.5)

// ---------------- workspace layout (bytes) ----------------
#define OFF_SEQ    0          // 65536 f32              -> 262144
#define OFF_CURSOR 262144     // 8192 i32 (zeroed in seq_kernel) -> 294912
#define OFF_ROWCNT 294912     // 8192 i32               -> 327680
#define OFF_JV     327680     // 8192*256 int2 (16 MB)  -> 17104896
#define OFF_JW     17104896   // 8192*256 int2 (16 MB)  -> 33882112
#define WS_NEEDED  33882112

// seq[r] = dot(rel[r, 0:64], W[0, 0:64]); also zeroes cursor (r < N_NODES)
__global__ void seq_kernel(const float* __restrict__ rel,
                           const float* __restrict__ W,
                           float* __restrict__ seq,
                           int* __restrict__ cursor) {
    int r = blockIdx.x * blockDim.x + threadIdx.x;
    if (r < N_NODES) cursor[r] = 0;
    if (r >= RCOUNT) return;
    const float4* rr = reinterpret_cast<const float4*>(rel + (size_t)r * IN_RELS);
    const float4* ww = reinterpret_cast<const float4*>(W);
    float acc = 0.f;
#pragma unroll
    for (int k = 0; k < IN_RELS / 4; ++k) {
        float4 a = rr[k];
        float4 w = ww[k];
        acc += a.x * w.x + a.y * w.y + a.z * w.z + a.w * w.w;
    }
    seq[r] = acc;
}

// Direct scatter: pair p -> row slot (no CSR). One packed 8B store per pair.
__global__ void scatter_direct_kernel(const int* __restrict__ src,
                                      const int* __restrict__ dst,
                                      const int* __restrict__ prel,
                                      const float* __restrict__ seq,
                                      int* __restrict__ cursor,
                                      int2* __restrict__ jv) {
    int p = blockIdx.x * blockDim.x + threadIdx.x;
    if (p >= M_PAIRS) return;
    int s = src[p];
    if (s < 0 || s >= N_NODES) return;
    int j = dst[p];
    if (j < 0 || j >= N_NODES) return;
    int r = prel[p];
    if (r < 0 || r >= RCOUNT) return;
    int pos = atomicAdd(&cursor[s], 1);
    if (pos < LCAP) {
        float v = fmaxf(seq[r], 0.f);   // zeros-init scatter-max == clamp at 0
        jv[(size_t)s * LCAP + pos] = make_int2(j, __float_as_int(v));
    }
}

// Per row: hash dedup/max (512-slot LDS), softmax over unique set, write (j,w)
// interleaved. Wave-level shfl reductions: 6 barriers total.
__launch_bounds__(256)
__global__ void attn_hash_kernel(const int2* __restrict__ jv,
                                 const int* __restrict__ cursor,
                                 int2* __restrict__ jw,
                                 int* __restrict__ rowcnt) {
    __shared__ int   hkey[HSIZE];
    __shared__ int   hval[HSIZE];
    __shared__ float redm[4];
    __shared__ float redz[4];
    __shared__ int   nout;

    const int i    = blockIdx.x;
    const int t    = threadIdx.x;
    const int lane = t & 63;
    const int wid  = t >> 6;

    hkey[t] = -1;       hkey[t + 256] = -1;
    hval[t] = -1;       hval[t + 256] = -1;
    if (t == 0) nout = 0;
    __syncthreads();

    int cnt = cursor[i];
    if (cnt < 0) cnt = 0;
    if (cnt > LCAP) cnt = LCAP;

    for (int e = t; e < cnt; e += 256) {
        int2 p = jv[(size_t)i * LCAP + e];
        int j = p.x;
        unsigned slot = ((unsigned)j * 2654435761u >> 16) & (HSIZE - 1);
        for (;;) {
            int k = atomicCAS(&hkey[slot], -1, j);
            if (k == -1 || k == j) break;
            slot = (slot + 1) & (HSIZE - 1);
        }
        atomicMax(&hval[slot], p.y);   // p.y >= 0 as int (float bits of v>=0)
    }
    if (t == 0) {                      // self-loop, value 0.0f (bits == 0)
        int j = i;
        unsigned slot = ((unsigned)j * 2654435761u >> 16) & (HSIZE - 1);
        for (;;) {
            int k = atomicCAS(&hkey[slot], -1, j);
            if (k == -1 || k == j) break;
            slot = (slot + 1) & (HSIZE - 1);
        }
        atomicMax(&hval[slot], 0);
    }
    __syncthreads();

    // snapshot this thread's two slots
    const int   k0 = hkey[t];
    const int   k1 = hkey[t + 256];
    const float v0 = __int_as_float(hval[t]);
    const float v1 = __int_as_float(hval[t + 256]);

    // row max (all present values >= 0; self-loop guarantees at least one)
    float m = 0.f;
    if (k0 >= 0) m = fmaxf(m, v0);
    if (k1 >= 0) m = fmaxf(m, v1);
#pragma unroll
    for (int off = 32; off > 0; off >>= 1) m = fmaxf(m, __shfl_xor(m, off, 64));
    if (lane == 0) redm[wid] = m;
    __syncthreads();
    m = fmaxf(fmaxf(redm[0], redm[1]), fmaxf(redm[2], redm[3]));

    // exp once, keep in registers; wave-reduce the denominator
    float e0 = 0.f, e1 = 0.f, z = 0.f;
    if (k0 >= 0) { e0 = expf(v0 - m); z += e0; }
    if (k1 >= 0) { e1 = expf(v1 - m); z += e1; }
#pragma unroll
    for (int off = 32; off > 0; off >>= 1) z += __shfl_xor(z, off, 64);
    if (lane == 0) redz[wid] = z;
    __syncthreads();
    const float invZ = 1.f / (((redz[0] + redz[1]) + (redz[2] + redz[3])));

    // compact normalized weights (interleaved j,w)
    if (k0 >= 0) {
        int idx = atomicAdd(&nout, 1);
        if (idx < LCAP) jw[(size_t)i * LCAP + idx] = make_int2(k0, __float_as_int(e0 * invZ));
    }
    if (k1 >= 0) {
        int idx = atomicAdd(&nout, 1);
        if (idx < LCAP) jw[(size_t)i * LCAP + idx] = make_int2(k1, __float_as_int(e1 * invZ));
    }
    __syncthreads();
    if (t == 0) rowcnt[i] = nout < LCAP ? nout : LCAP;
}

// grid (8192 rows, 4 feature-quarters), 64 threads (1 wave). y-major dispatch
// keeps the active x working set at 2 MB (= half an XCD L2).
__launch_bounds__(64)
__global__ void spmm_kernel(const float* __restrict__ x,
                            const float* __restrict__ bias,
                            const int2* __restrict__ jw,
                            const int* __restrict__ rowcnt,
                            float* __restrict__ out) {
    __shared__ int2 s[LCAP];
    const int row = blockIdx.x;
    const int q   = blockIdx.y;
    const int t   = threadIdx.x;

    int cnt = rowcnt[row];
    if (cnt < 0) cnt = 0;
    if (cnt > LCAP) cnt = LCAP;
    for (int e = t; e < cnt; e += 64) s[e] = jw[(size_t)row * LCAP + e];
    __syncthreads();

    const float* xq = x + (size_t)q * 64 + t;
    float a0 = 0.f, a1 = 0.f, a2 = 0.f, a3 = 0.f;
    float a4 = 0.f, a5 = 0.f, a6 = 0.f, a7 = 0.f;
    int e = 0;
    for (; e + 8 <= cnt; e += 8) {
        a0 += __int_as_float(s[e + 0].y) * xq[(size_t)s[e + 0].x * FEATDIM];
        a1 += __int_as_float(s[e + 1].y) * xq[(size_t)s[e + 1].x * FEATDIM];
        a2 += __int_as_float(s[e + 2].y) * xq[(size_t)s[e + 2].x * FEATDIM];
        a3 += __int_as_float(s[e + 3].y) * xq[(size_t)s[e + 3].x * FEATDIM];
        a4 += __int_as_float(s[e + 4].y) * xq[(size_t)s[e + 4].x * FEATDIM];
        a5 += __int_as_float(s[e + 5].y) * xq[(size_t)s[e + 5].x * FEATDIM];
        a6 += __int_as_float(s[e + 6].y) * xq[(size_t)s[e + 6].x * FEATDIM];
        a7 += __int_as_float(s[e + 7].y) * xq[(size_t)s[e + 7].x * FEATDIM];
    }
    for (; e < cnt; ++e) a0 += __int_as_float(s[e].y) * xq[(size_t)s[e].x * FEATDIM];
    float v = ((a0 + a1) + (a2 + a3)) + ((a4 + a5) + (a6 + a7)) + bias[q * 64 + t];
    out[(size_t)row * FEATDIM + q * 64 + t] = v > 0.f ? v : expm1f(v);
}

extern "C" void kernel_launch(void* const* d_in, const int* in_sizes, int n_in,
                              void* d_out, int out_size, void* d_ws, size_t ws_size,
                              hipStream_t stream) {
    // defensive gates: clean validation failure beats a dead container
    if (ws_size < (size_t)WS_NEEDED) return;
    if (out_size < N_NODES * FEATDIM) return;
    if (n_in < 8) return;

    const float* x        = (const float*)d_in[0];
    const float* rel      = (const float*)d_in[1];
    const float* W        = (const float*)d_in[2];
    const float* bias     = (const float*)d_in[3];
    // d_in[4] = adj : intentionally unused (softmax reconstructed sparsely;
    // exp(-1e9 - m) underflows to exact fp32 zero, so dense == sparse)
    const int*   pair_src = (const int*)d_in[5];
    const int*   pair_dst = (const int*)d_in[6];
    const int*   pair_rel = (const int*)d_in[7];
    float* out = (float*)d_out;

    char* ws = (char*)d_ws;
    float* seq    = (float*)(ws + OFF_SEQ);
    int*   cursor = (int*)(ws + OFF_CURSOR);
    int*   rowcnt = (int*)(ws + OFF_ROWCNT);
    int2*  jv     = (int2*)(ws + OFF_JV);
    int2*  jw     = (int2*)(ws + OFF_JW);

    seq_kernel<<<RCOUNT / 256, 256, 0, stream>>>(rel, W, seq, cursor);
    scatter_direct_kernel<<<M_PAIRS / 256, 256, 0, stream>>>(pair_src, pair_dst,
                                                             pair_rel, seq, cursor, jv);
    attn_hash_kernel<<<N_NODES, 256, 0, stream>>>(jv, cursor, jw, rowcnt);
    spmm_kernel<<<dim3(N_NODES, 4), 64, 0, stream>>>(x, bias, jw, rowcnt, out);
}